// Round 1
// baseline (709.390 us; speedup 1.0000x reference)
//
#include <hip/hip_runtime.h>
#include <hip/hip_bf16.h>
#include <math.h>

#define BATCH 2
#define NSEQ 2048
#define DIM 512
#define HEADS 8
#define DH 64
#define NTOK (BATCH * NSEQ)          // 4096
#define CHUNK 32                     // query rows per chunk (attention)
#define PANEL 64                     // global keys covered per staged panel

// ---------------------------------------------------------------------------
// LayerNorm over last dim (512). One block of 128 threads per row.
// ---------------------------------------------------------------------------
__global__ __launch_bounds__(128) void ln_kernel(
    const float* __restrict__ x, const float* __restrict__ gamma,
    const float* __restrict__ beta, float* __restrict__ xn)
{
    int row = blockIdx.x;
    int tid = threadIdx.x;
    float4 v = ((const float4*)(x + (size_t)row * DIM))[tid];
    float s  = v.x + v.y + v.z + v.w;
    float s2 = v.x*v.x + v.y*v.y + v.z*v.z + v.w*v.w;
    #pragma unroll
    for (int off = 32; off > 0; off >>= 1) {
        s  += __shfl_down(s,  off);
        s2 += __shfl_down(s2, off);
    }
    __shared__ float red[4];
    if ((tid & 63) == 0) { red[(tid >> 6) * 2] = s; red[(tid >> 6) * 2 + 1] = s2; }
    __syncthreads();
    float S  = red[0] + red[2];
    float S2 = red[1] + red[3];
    float mu  = S * (1.0f / DIM);
    float var = S2 * (1.0f / DIM) - mu * mu;
    float inv = rsqrtf(var + 1e-5f);
    float4 g  = ((const float4*)gamma)[tid];
    float4 be = ((const float4*)beta)[tid];
    float4 o;
    o.x = (v.x - mu) * inv * g.x + be.x;
    o.y = (v.y - mu) * inv * g.y + be.y;
    o.z = (v.z - mu) * inv * g.z + be.z;
    o.w = (v.w - mu) * inv * g.w + be.w;
    ((float4*)(xn + (size_t)row * DIM))[tid] = o;
}

// ---------------------------------------------------------------------------
// C[m, n] = sum_k A[m, k] * W[n, k]    (A: [M,K] rm, W: [N,K] rm, C: [M,N] rm)
// 64x64 tile, 16 k-step, 256 threads, 4x4 contiguous microtile.
// ---------------------------------------------------------------------------
__global__ __launch_bounds__(256) void gemm_nt(
    const float* __restrict__ A, const float* __restrict__ W,
    float* __restrict__ C, int M, int N, int Kd)
{
    __shared__ float As[16][68];   // [k][m], 68 stride keeps float4 rows 16B-aligned
    __shared__ float Bs[16][68];   // [k][n]
    int tid = threadIdx.x;
    int m0 = blockIdx.y * 64;
    int n0 = blockIdx.x * 64;
    int ty = tid >> 4, tx = tid & 15;          // 16x16 threads
    int lm = tid >> 2;                         // load row 0..63
    int lk = (tid & 3) * 4;                    // load col 0,4,8,12
    float acc[4][4] = {};
    for (int k0 = 0; k0 < Kd; k0 += 16) {
        float4 a4 = *(const float4*)(A + (size_t)(m0 + lm) * Kd + k0 + lk);
        float4 b4 = *(const float4*)(W + (size_t)(n0 + lm) * Kd + k0 + lk);
        __syncthreads();
        As[lk + 0][lm] = a4.x; As[lk + 1][lm] = a4.y;
        As[lk + 2][lm] = a4.z; As[lk + 3][lm] = a4.w;
        Bs[lk + 0][lm] = b4.x; Bs[lk + 1][lm] = b4.y;
        Bs[lk + 2][lm] = b4.z; Bs[lk + 3][lm] = b4.w;
        __syncthreads();
        #pragma unroll
        for (int kk = 0; kk < 16; kk++) {
            float4 av = *(const float4*)&As[kk][ty * 4];
            float4 bv = *(const float4*)&Bs[kk][tx * 4];
            float a[4] = {av.x, av.y, av.z, av.w};
            float b[4] = {bv.x, bv.y, bv.z, bv.w};
            #pragma unroll
            for (int i = 0; i < 4; i++)
                #pragma unroll
                for (int j = 0; j < 4; j++)
                    acc[i][j] = fmaf(a[i], b[j], acc[i][j]);
        }
    }
    #pragma unroll
    for (int i = 0; i < 4; i++) {
        float4 o = make_float4(acc[i][0], acc[i][1], acc[i][2], acc[i][3]);
        *(float4*)(C + (size_t)(m0 + ty * 4 + i) * N + n0 + tx * 4) = o;
    }
}

// ---------------------------------------------------------------------------
// Depthwise causal conv (kernel 3) + head split (+ q scale).
// out[n] = wd0*y[n-2] + wd1*y[n-1] + wd2*y[n]; dst layout [b,h,n,d].
// ---------------------------------------------------------------------------
__global__ __launch_bounds__(256) void dwconv_kernel(
    const float* __restrict__ yq, const float* __restrict__ yk, const float* __restrict__ yv,
    const float* __restrict__ wqd, const float* __restrict__ wkd, const float* __restrict__ wvd,
    float* __restrict__ q, float* __restrict__ k, float* __restrict__ v)
{
    int which = blockIdx.z;
    const float* y  = which == 0 ? yq  : which == 1 ? yk  : yv;
    const float* wd = which == 0 ? wqd : which == 1 ? wkd : wvd;
    float* dst      = which == 0 ? q   : which == 1 ? k   : v;
    float scale     = which == 0 ? 0.125f : 1.0f;   // DH^-0.5 = 1/8
    int idx = blockIdx.x * 256 + threadIdx.x;       // 0 .. NTOK*DIM-1
    int e = idx & (DIM - 1);
    int t = idx >> 9;
    int n = t & (NSEQ - 1);
    float y0 = y[(size_t)t * DIM + e];
    float y1 = (n >= 1) ? y[(size_t)(t - 1) * DIM + e] : 0.0f;
    float y2 = (n >= 2) ? y[(size_t)(t - 2) * DIM + e] : 0.0f;
    float w0 = wd[e * 3 + 0], w1 = wd[e * 3 + 1], w2 = wd[e * 3 + 2];
    float r = (w0 * y2 + w1 * y1 + w2 * y0) * scale;
    int b = t >> 11;
    int h = e >> 6, d = e & 63;
    dst[(((size_t)(b * HEADS + h)) * NSEQ + n) * DH + d] = r;
}

// ---------------------------------------------------------------------------
// Flash-style causal attention with ALiBi. fp32, no running max (scores <= ~1).
// Block = 64 threads (1 wave). Lane (r, half): row = chunk*32 + r, d-half.
// Each block handles chunk pair {p, 63-p} (uniform work) for key parity s.
// Writes unnormalized o-sums and l-sums per (split, b, h, row).
// ---------------------------------------------------------------------------
__global__ __launch_bounds__(64) void attn_kernel(
    const float* __restrict__ Q, const float* __restrict__ K,
    const float* __restrict__ V, float* __restrict__ pl, float* __restrict__ po)
{
    __shared__ float Ks[32][DH];
    __shared__ float Vs[32][DH];
    int pair = blockIdx.x;        // 0..31
    int bh   = blockIdx.y;        // 0..15
    int s    = blockIdx.z;        // key parity 0/1
    int h    = bh & (HEADS - 1);
    float slope = exp2f(-(float)(h + 1));
    int lane  = threadIdx.x;
    int r     = lane & 31;
    int half  = lane >> 5;
    int dbase = half * 32;
    const float* Qb = Q + (size_t)bh * NSEQ * DH;
    const float* Kb = K + (size_t)bh * NSEQ * DH;
    const float* Vb = V + (size_t)bh * NSEQ * DH;

    for (int ci = 0; ci < 2; ci++) {
        int c = ci ? (63 - pair) : pair;
        int row = c * CHUNK + r;
        float qr[32];
        const float4* qp = (const float4*)(Qb + (size_t)row * DH + dbase);
        #pragma unroll
        for (int t = 0; t < 8; t++) {
            float4 v4 = qp[t];
            qr[t*4+0] = v4.x; qr[t*4+1] = v4.y; qr[t*4+2] = v4.z; qr[t*4+3] = v4.w;
        }
        float o[32];
        #pragma unroll
        for (int t = 0; t < 32; t++) o[t] = 0.0f;
        float lsum = 0.0f;
        int rowmax  = c * CHUNK + CHUNK - 1;
        int npanels = (rowmax + PANEL) / PANEL;
        for (int kp = 0; kp < npanels; kp++) {
            int jb0 = kp * PANEL;
            __syncthreads();
            // stage 32 parity-s keys covering global keys [jb0, jb0+64)
            #pragma unroll
            for (int it = 0; it < 8; it++) {
                int fidx = it * 64 + lane;     // 0..511 float4 slots
                int rr = fidx >> 4;            // staged row 0..31
                int c4 = fidx & 15;
                int j = jb0 + rr * 2 + s;
                float4 kv4 = make_float4(0, 0, 0, 0), vv4 = make_float4(0, 0, 0, 0);
                if (j < NSEQ) {
                    kv4 = ((const float4*)(Kb + (size_t)j * DH))[c4];
                    vv4 = ((const float4*)(Vb + (size_t)j * DH))[c4];
                }
                ((float4*)&Ks[rr][0])[c4] = kv4;
                ((float4*)&Vs[rr][0])[c4] = vv4;
            }
            __syncthreads();
            // per-lane valid staged-key count: j = jb0 + 2*jj + s <= row
            int lim = row - jb0 - s;
            int jjcnt = (lim < 0) ? 0 : ((lim >> 1) + 1);
            if (jjcnt > 32) jjcnt = 32;
            for (int jj = 0; jj < jjcnt; jj++) {
                int j = jb0 + jj * 2 + s;
                float a0 = 0, a1 = 0, a2 = 0, a3 = 0;
                #pragma unroll
                for (int t = 0; t < 32; t += 4) {
                    a0 = fmaf(qr[t + 0], Ks[jj][dbase + t + 0], a0);
                    a1 = fmaf(qr[t + 1], Ks[jj][dbase + t + 1], a1);
                    a2 = fmaf(qr[t + 2], Ks[jj][dbase + t + 2], a2);
                    a3 = fmaf(qr[t + 3], Ks[jj][dbase + t + 3], a3);
                }
                float part = (a0 + a1) + (a2 + a3);
                float sfull = part + __shfl_xor(part, 32);
                sfull += slope * (float)(j - row);       // ALiBi (j<=row)
                float p = __expf(sfull);
                lsum += p;
                #pragma unroll
                for (int t = 0; t < 32; t++)
                    o[t] = fmaf(p, Vs[jj][dbase + t], o[t]);
            }
        }
        size_t rbh = ((size_t)s * (BATCH * HEADS) + bh) * NSEQ + row;
        if (half == 0) pl[rbh] = lsum;
        float* pop = po + rbh * DH + dbase;
        #pragma unroll
        for (int t = 0; t < 8; t++)
            ((float4*)pop)[t] = make_float4(o[t*4], o[t*4+1], o[t*4+2], o[t*4+3]);
    }
}

// ---------------------------------------------------------------------------
// Merge the two key-parity splits and write attn output as [b, n, h*64+d].
// ---------------------------------------------------------------------------
__global__ __launch_bounds__(256) void merge_kernel(
    const float* __restrict__ pl, const float* __restrict__ po,
    float* __restrict__ attn_out)
{
    int idx = blockIdx.x * 256 + threadIdx.x;   // 0 .. 16*2048*64-1
    int d = idx & 63;
    size_t rbh = (size_t)(idx >> 6);            // bh*NSEQ + n
    int n  = (int)(rbh & (NSEQ - 1));
    int bh = (int)(rbh >> 11);
    const size_t SPLIT = (size_t)(BATCH * HEADS) * NSEQ;  // 32768
    float l0 = pl[rbh], l1 = pl[SPLIT + rbh];
    float o0 = po[rbh * DH + d], o1 = po[(SPLIT + rbh) * DH + d];
    int b = bh >> 3, h = bh & 7;
    attn_out[((size_t)(b * NSEQ + n)) * DIM + h * DH + d] = (o0 + o1) / (l0 + l1);
}

// ---------------------------------------------------------------------------
extern "C" void kernel_launch(void* const* d_in, const int* in_sizes, int n_in,
                              void* d_out, int out_size, void* d_ws, size_t ws_size,
                              hipStream_t stream)
{
    (void)in_sizes; (void)n_in; (void)out_size; (void)ws_size;
    const float* x     = (const float*)d_in[0];
    const float* gamma = (const float*)d_in[1];
    const float* beta  = (const float*)d_in[2];
    const float* wq1   = (const float*)d_in[3];
    const float* wqd   = (const float*)d_in[4];
    const float* wk1   = (const float*)d_in[5];
    const float* wkd   = (const float*)d_in[6];
    const float* wv1   = (const float*)d_in[7];
    const float* wvd   = (const float*)d_in[8];
    const float* wout  = (const float*)d_in[9];
    float* out = (float*)d_out;
    float* ws  = (float*)d_ws;

    const size_t M1 = (size_t)NTOK * DIM;   // 2M floats
    float* xn   = ws;
    float* yq   = ws + 1 * M1;
    float* yk   = ws + 2 * M1;
    float* yv   = ws + 3 * M1;
    float* q    = ws + 4 * M1;
    float* k    = ws + 5 * M1;
    float* v    = ws + 6 * M1;
    float* po   = ws + 7 * M1;              // [2][16][2048][64] = 2*M1
    float* pl   = ws + 9 * M1;              // [2][16][2048]
    float* attn = ws + 10 * M1;

    ln_kernel<<<NTOK, 128, 0, stream>>>(x, gamma, beta, xn);
    gemm_nt<<<dim3(DIM / 64, NTOK / 64), 256, 0, stream>>>(xn, wq1, yq, NTOK, DIM, DIM);
    gemm_nt<<<dim3(DIM / 64, NTOK / 64), 256, 0, stream>>>(xn, wk1, yk, NTOK, DIM, DIM);
    gemm_nt<<<dim3(DIM / 64, NTOK / 64), 256, 0, stream>>>(xn, wv1, yv, NTOK, DIM, DIM);
    dwconv_kernel<<<dim3(NTOK * DIM / 256, 1, 3), 256, 0, stream>>>(
        yq, yk, yv, wqd, wkd, wvd, q, k, v);
    attn_kernel<<<dim3(32, BATCH * HEADS, 2), 64, 0, stream>>>(q, k, v, pl, po);
    merge_kernel<<<(BATCH * HEADS * NSEQ * DH) / 256, 256, 0, stream>>>(pl, po, attn);
    gemm_nt<<<dim3(DIM / 64, NTOK / 64), 256, 0, stream>>>(attn, wout, out, NTOK, DIM, DIM);
}

// Round 2
// 313.488 us; speedup vs baseline: 2.2629x; 2.2629x over previous
//
#include <hip/hip_runtime.h>
#include <hip/hip_bf16.h>
#include <math.h>

#define BATCH 2
#define NSEQ 2048
#define DIM 512
#define HEADS 8
#define DH 64
#define NTOK (BATCH * NSEQ)          // 4096

typedef short short8 __attribute__((ext_vector_type(8)));   // 8 bf16 (4 VGPR)
typedef float f32x16 __attribute__((ext_vector_type(16)));  // MFMA 32x32 acc
typedef __hip_bfloat16 bf16;

// ---------------------------------------------------------------------------
// LayerNorm over last dim (512). One block of 128 threads per row.
// ---------------------------------------------------------------------------
__global__ __launch_bounds__(128) void ln_kernel(
    const float* __restrict__ x, const float* __restrict__ gamma,
    const float* __restrict__ beta, float* __restrict__ xn)
{
    int row = blockIdx.x;
    int tid = threadIdx.x;
    float4 v = ((const float4*)(x + (size_t)row * DIM))[tid];
    float s  = v.x + v.y + v.z + v.w;
    float s2 = v.x*v.x + v.y*v.y + v.z*v.z + v.w*v.w;
    #pragma unroll
    for (int off = 32; off > 0; off >>= 1) {
        s  += __shfl_down(s,  off);
        s2 += __shfl_down(s2, off);
    }
    __shared__ float red[4];
    if ((tid & 63) == 0) { red[(tid >> 6) * 2] = s; red[(tid >> 6) * 2 + 1] = s2; }
    __syncthreads();
    float S  = red[0] + red[2];
    float S2 = red[1] + red[3];
    float mu  = S * (1.0f / DIM);
    float var = S2 * (1.0f / DIM) - mu * mu;
    float inv = rsqrtf(var + 1e-5f);
    float4 g  = ((const float4*)gamma)[tid];
    float4 be = ((const float4*)beta)[tid];
    float4 o;
    o.x = (v.x - mu) * inv * g.x + be.x;
    o.y = (v.y - mu) * inv * g.y + be.y;
    o.z = (v.z - mu) * inv * g.z + be.z;
    o.w = (v.w - mu) * inv * g.w + be.w;
    ((float4*)(xn + (size_t)row * DIM))[tid] = o;
}

// ---------------------------------------------------------------------------
// C[m, n] = sum_k A[m, k] * W[n, k]  (fp32 vector-ALU GEMM, 64x64 tile)
// ---------------------------------------------------------------------------
__global__ __launch_bounds__(256) void gemm_nt(
    const float* __restrict__ A, const float* __restrict__ W,
    float* __restrict__ C, int M, int N, int Kd)
{
    __shared__ float As[16][68];
    __shared__ float Bs[16][68];
    int tid = threadIdx.x;
    int m0 = blockIdx.y * 64;
    int n0 = blockIdx.x * 64;
    int ty = tid >> 4, tx = tid & 15;
    int lm = tid >> 2;
    int lk = (tid & 3) * 4;
    float acc[4][4] = {};
    for (int k0 = 0; k0 < Kd; k0 += 16) {
        float4 a4 = *(const float4*)(A + (size_t)(m0 + lm) * Kd + k0 + lk);
        float4 b4 = *(const float4*)(W + (size_t)(n0 + lm) * Kd + k0 + lk);
        __syncthreads();
        As[lk + 0][lm] = a4.x; As[lk + 1][lm] = a4.y;
        As[lk + 2][lm] = a4.z; As[lk + 3][lm] = a4.w;
        Bs[lk + 0][lm] = b4.x; Bs[lk + 1][lm] = b4.y;
        Bs[lk + 2][lm] = b4.z; Bs[lk + 3][lm] = b4.w;
        __syncthreads();
        #pragma unroll
        for (int kk = 0; kk < 16; kk++) {
            float4 av = *(const float4*)&As[kk][ty * 4];
            float4 bv = *(const float4*)&Bs[kk][tx * 4];
            float a[4] = {av.x, av.y, av.z, av.w};
            float b[4] = {bv.x, bv.y, bv.z, bv.w};
            #pragma unroll
            for (int i = 0; i < 4; i++)
                #pragma unroll
                for (int j = 0; j < 4; j++)
                    acc[i][j] = fmaf(a[i], b[j], acc[i][j]);
        }
    }
    #pragma unroll
    for (int i = 0; i < 4; i++) {
        float4 o = make_float4(acc[i][0], acc[i][1], acc[i][2], acc[i][3]);
        *(float4*)(C + (size_t)(m0 + ty * 4 + i) * N + n0 + tx * 4) = o;
    }
}

// ---------------------------------------------------------------------------
// Depthwise causal conv (kernel 3) + head split (+ q scale), bf16 output.
// dst layout [b,h,n,d] row-major bf16.
// ---------------------------------------------------------------------------
__global__ __launch_bounds__(256) void dwconv_kernel(
    const float* __restrict__ yq, const float* __restrict__ yk, const float* __restrict__ yv,
    const float* __restrict__ wqd, const float* __restrict__ wkd, const float* __restrict__ wvd,
    bf16* __restrict__ q, bf16* __restrict__ k, bf16* __restrict__ v)
{
    int which = blockIdx.z;
    const float* y  = which == 0 ? yq  : which == 1 ? yk  : yv;
    const float* wd = which == 0 ? wqd : which == 1 ? wkd : wvd;
    bf16* dst       = which == 0 ? q   : which == 1 ? k   : v;
    float scale     = which == 0 ? 0.125f : 1.0f;   // DH^-0.5 = 1/8
    int idx = blockIdx.x * 256 + threadIdx.x;       // 0 .. NTOK*DIM-1
    int e = idx & (DIM - 1);
    int t = idx >> 9;
    int n = t & (NSEQ - 1);
    float y0 = y[(size_t)t * DIM + e];
    float y1 = (n >= 1) ? y[(size_t)(t - 1) * DIM + e] : 0.0f;
    float y2 = (n >= 2) ? y[(size_t)(t - 2) * DIM + e] : 0.0f;
    float w0 = wd[e * 3 + 0], w1 = wd[e * 3 + 1], w2 = wd[e * 3 + 2];
    float r = (w0 * y2 + w1 * y1 + w2 * y0) * scale;
    int b = t >> 11;
    int h = e >> 6, d = e & 63;
    dst[(((size_t)(b * HEADS + h)) * NSEQ + n) * DH + d] = __float2bfloat16(r);
}

// ---------------------------------------------------------------------------
// V transpose: v[bh][n][d] -> vT[bh][d][n]  (bf16). 64x64 tiles via LDS.
// ---------------------------------------------------------------------------
__global__ __launch_bounds__(256) void vtrans_kernel(
    const bf16* __restrict__ v, bf16* __restrict__ vT)
{
    __shared__ unsigned short L[64][72];   // 144B row stride: 16B aligned
    int bh = blockIdx.y;
    int n0 = blockIdx.x * 64;
    int tid = threadIdx.x;
    const unsigned short* src = (const unsigned short*)v + ((size_t)bh * NSEQ + n0) * DH;
    #pragma unroll
    for (int it = 0; it < 2; it++) {
        int idx = it * 256 + tid;
        int r = idx >> 3, c = (idx & 7) * 8;
        *(short8*)&L[r][c] = *(const short8*)(src + (size_t)r * DH + c);
    }
    __syncthreads();
    unsigned short* dst = (unsigned short*)vT + (size_t)bh * DH * NSEQ + n0;
    #pragma unroll
    for (int it = 0; it < 2; it++) {
        int idx = it * 256 + tid;
        int d = idx >> 3, c8 = (idx & 7) * 8;
        short8 o;
        #pragma unroll
        for (int t = 0; t < 8; t++) o[t] = (short)L[c8 + t][d];
        *(short8*)(dst + (size_t)d * NSEQ + c8) = o;
    }
}

// ---------------------------------------------------------------------------
// MFMA flash attention, 1 wave per 32-row Q tile, no LDS, no barriers.
// ST = mfma(K, Q): lane holds col i = lane&31, 16 j's in regs.
// P -> bf16 A-frag via cvt_pk + permlane32_swap (T12).  PV B-frag from vT.
// No running max: scores = dot(~1e-2) + alibi(<=0) -> exp in [0, ~1.01].
// ---------------------------------------------------------------------------
template<bool MASKED>
__device__ __forceinline__ void attn_step(
    int j0, int il, int hi, int i_global,
    const bf16* __restrict__ Kb, const bf16* __restrict__ VTb,
    const short8* qf, const float* bconst, float slope2,
    f32x16& o0, f32x16& o1, float& lsum)
{
    short8 kf[4];
    const short8* krow = (const short8*)(Kb + (size_t)(j0 + il) * DH);
    #pragma unroll
    for (int c = 0; c < 4; c++) kf[c] = krow[2 * c + hi];
    f32x16 st = {};
    #pragma unroll
    for (int c = 0; c < 4; c++)
        st = __builtin_amdgcn_mfma_f32_32x32x16_bf16(kf[c], qf[c], st, 0, 0, 0);
    // softmax (unnormalized): p = exp2(st*log2e + slope2*(j - i))
    float sdb = slope2 * (float)(j0 - i_global);
    float p[16];
    #pragma unroll
    for (int r = 0; r < 16; r++) {
        float e = fmaf(st[r], 1.4426950408889634f, sdb + bconst[r]);
        float pr = exp2f(e);
        if (MASKED) {
            int jl = (r & 3) + 8 * (r >> 2) + 4 * hi;
            pr = (jl <= il) ? pr : 0.0f;   // j0==i0 here: j<=i  <=>  jl<=il
        }
        p[r] = pr;
        lsum += pr;
    }
    // pack P to bf16 words; w[2g],w[2g+1] cover j-run 8g+4hi .. +3
    unsigned w[8];
    #pragma unroll
    for (int g = 0; g < 4; g++) {
        asm("v_cvt_pk_bf16_f32 %0, %1, %2" : "=v"(w[2*g])   : "v"(p[4*g]),   "v"(p[4*g+1]));
        asm("v_cvt_pk_bf16_f32 %0, %1, %2" : "=v"(w[2*g+1]) : "v"(p[4*g+2]), "v"(p[4*g+3]));
    }
    const unsigned short* vt = (const unsigned short*)VTb;
    #pragma unroll
    for (int jc = 0; jc < 2; jc++) {
        unsigned x0 = w[4*jc], x1 = w[4*jc+1], y0 = w[4*jc+2], y1 = w[4*jc+3];
        asm("v_permlane32_swap_b32 %0, %1" : "+v"(x0), "+v"(y0));
        asm("v_permlane32_swap_b32 %0, %1" : "+v"(x1), "+v"(y1));
        union { unsigned u[4]; short8 s; } pa;
        pa.u[0] = x0; pa.u[1] = x1; pa.u[2] = y0; pa.u[3] = y1;
        const short8* vr0 = (const short8*)(vt + (size_t)(il)      * NSEQ + j0 + jc * 16);
        const short8* vr1 = (const short8*)(vt + (size_t)(32 + il) * NSEQ + j0 + jc * 16);
        o0 = __builtin_amdgcn_mfma_f32_32x32x16_bf16(pa.s, vr0[hi], o0, 0, 0, 0);
        o1 = __builtin_amdgcn_mfma_f32_32x32x16_bf16(pa.s, vr1[hi], o1, 0, 0, 0);
    }
}

__global__ __launch_bounds__(64) void attn_mfma(
    const bf16* __restrict__ Q, const bf16* __restrict__ K,
    const bf16* __restrict__ VT, float* __restrict__ attn_out)
{
    int bh = blockIdx.y;
    int b = bh >> 3, h = bh & 7;
    int ti = (blockIdx.x + 13 * blockIdx.y) & 63;   // spread heavy tiles across CUs
    int i0 = ti * 32;
    int lane = threadIdx.x;
    int il = lane & 31, hi = lane >> 5;
    int i_global = i0 + il;
    float slope  = exp2f(-(float)(h + 1));
    float slope2 = slope * 1.4426950408889634f;     // slope * log2(e)
    float bconst[16];
    #pragma unroll
    for (int r = 0; r < 16; r++) {
        int jl = (r & 3) + 8 * (r >> 2) + 4 * hi;
        bconst[r] = slope2 * (float)jl;
    }
    const bf16* Qb  = Q  + (size_t)bh * NSEQ * DH;
    const bf16* Kb  = K  + (size_t)bh * NSEQ * DH;
    const bf16* VTb = VT + (size_t)bh * DH * NSEQ;
    short8 qf[4];
    const short8* qrow = (const short8*)(Qb + (size_t)(i0 + il) * DH);
    #pragma unroll
    for (int c = 0; c < 4; c++) qf[c] = qrow[2 * c + hi];
    f32x16 o0 = {}, o1 = {};
    float lsum = 0.0f;
    for (int kt = 0; kt < ti; kt++)
        attn_step<false>(kt * 32, il, hi, i_global, Kb, VTb, qf, bconst, slope2, o0, o1, lsum);
    attn_step<true>(ti * 32, il, hi, i_global, Kb, VTb, qf, bconst, slope2, o0, o1, lsum);

    float ltot = lsum + __shfl_xor(lsum, 32);       // lanes i and i+32 hold l[i]
    float* outb = attn_out + (size_t)b * NSEQ * DIM + h * DH;
    #pragma unroll
    for (int r = 0; r < 16; r++) {
        int irow = (r & 3) + 8 * (r >> 2) + 4 * hi;
        float lr = __shfl(ltot, irow);
        float inv = 1.0f / lr;
        size_t base = (size_t)(i0 + irow) * DIM;
        outb[base + il]      = o0[r] * inv;
        outb[base + 32 + il] = o1[r] * inv;
    }
}

// ---------------------------------------------------------------------------
extern "C" void kernel_launch(void* const* d_in, const int* in_sizes, int n_in,
                              void* d_out, int out_size, void* d_ws, size_t ws_size,
                              hipStream_t stream)
{
    (void)in_sizes; (void)n_in; (void)out_size; (void)ws_size;
    const float* x     = (const float*)d_in[0];
    const float* gamma = (const float*)d_in[1];
    const float* beta  = (const float*)d_in[2];
    const float* wq1   = (const float*)d_in[3];
    const float* wqd   = (const float*)d_in[4];
    const float* wk1   = (const float*)d_in[5];
    const float* wkd   = (const float*)d_in[6];
    const float* wv1   = (const float*)d_in[7];
    const float* wvd   = (const float*)d_in[8];
    const float* wout  = (const float*)d_in[9];
    float* out = (float*)d_out;
    float* ws  = (float*)d_ws;

    const size_t M1 = (size_t)NTOK * DIM;   // 2M floats
    float* xn   = ws;
    float* yq   = ws + 1 * M1;
    float* yk   = ws + 2 * M1;
    float* yv   = ws + 3 * M1;
    float* attn = ws + 4 * M1;
    bf16*  qb   = (bf16*)(ws + 5 * M1);     // 2M bf16 = 1M floats each
    bf16*  kb   = (bf16*)(ws + 6 * M1);
    bf16*  vb   = (bf16*)(ws + 7 * M1);
    bf16*  vtb  = (bf16*)(ws + 8 * M1);

    ln_kernel<<<NTOK, 128, 0, stream>>>(x, gamma, beta, xn);
    gemm_nt<<<dim3(DIM / 64, NTOK / 64), 256, 0, stream>>>(xn, wq1, yq, NTOK, DIM, DIM);
    gemm_nt<<<dim3(DIM / 64, NTOK / 64), 256, 0, stream>>>(xn, wk1, yk, NTOK, DIM, DIM);
    gemm_nt<<<dim3(DIM / 64, NTOK / 64), 256, 0, stream>>>(xn, wv1, yv, NTOK, DIM, DIM);
    dwconv_kernel<<<dim3(NTOK * DIM / 256, 1, 3), 256, 0, stream>>>(
        yq, yk, yv, wqd, wkd, wvd, qb, kb, vb);
    vtrans_kernel<<<dim3(NSEQ / 64, BATCH * HEADS), 256, 0, stream>>>(vb, vtb);
    attn_mfma<<<dim3(64, BATCH * HEADS), 64, 0, stream>>>(qb, kb, vtb, attn);
    gemm_nt<<<dim3(DIM / 64, NTOK / 64), 256, 0, stream>>>(attn, wout, out, NTOK, DIM, DIM);
}

// Round 4
// 180.145 us; speedup vs baseline: 3.9379x; 1.7402x over previous
//
#include <hip/hip_runtime.h>
#include <hip/hip_bf16.h>
#include <math.h>

#define BATCH 2
#define NSEQ 2048
#define DIM 512
#define HEADS 8
#define DH 64
#define NTOK (BATCH * NSEQ)          // 4096
#define NPROJ (3 * DIM)              // 1536

typedef short short8 __attribute__((ext_vector_type(8)));   // 8 bf16 (4 VGPR)
typedef short short4v __attribute__((ext_vector_type(4)));
typedef float f32x4 __attribute__((ext_vector_type(4)));
typedef float f32x16 __attribute__((ext_vector_type(16)));
typedef __hip_bfloat16 bf16;

static __device__ __forceinline__ short f2b(float f) {
    __hip_bfloat16 h = __float2bfloat16(f);
    return *(short*)&h;
}

static __device__ __forceinline__ void gload_lds16(const void* g, void* l) {
    __builtin_amdgcn_global_load_lds(
        (const __attribute__((address_space(1))) unsigned int*)g,
        (__attribute__((address_space(3))) unsigned int*)l, 16, 0, 0);
}

// ---------------------------------------------------------------------------
// LayerNorm over last dim (512), bf16 output. One block of 128 threads per row.
// ---------------------------------------------------------------------------
__global__ __launch_bounds__(128) void ln_kernel(
    const float* __restrict__ x, const float* __restrict__ gamma,
    const float* __restrict__ beta, bf16* __restrict__ xnb)
{
    int row = blockIdx.x;
    int tid = threadIdx.x;
    float4 v = ((const float4*)(x + (size_t)row * DIM))[tid];
    float s  = v.x + v.y + v.z + v.w;
    float s2 = v.x*v.x + v.y*v.y + v.z*v.z + v.w*v.w;
    #pragma unroll
    for (int off = 32; off > 0; off >>= 1) {
        s  += __shfl_down(s,  off);
        s2 += __shfl_down(s2, off);
    }
    __shared__ float red[4];
    if ((tid & 63) == 0) { red[(tid >> 6) * 2] = s; red[(tid >> 6) * 2 + 1] = s2; }
    __syncthreads();
    float S  = red[0] + red[2];
    float S2 = red[1] + red[3];
    float mu  = S * (1.0f / DIM);
    float var = S2 * (1.0f / DIM) - mu * mu;
    float inv = rsqrtf(var + 1e-5f);
    float4 g  = ((const float4*)gamma)[tid];
    float4 be = ((const float4*)beta)[tid];
    short4v o;
    o[0] = f2b((v.x - mu) * inv * g.x + be.x);
    o[1] = f2b((v.y - mu) * inv * g.y + be.y);
    o[2] = f2b((v.z - mu) * inv * g.z + be.z);
    o[3] = f2b((v.w - mu) * inv * g.w + be.w);
    ((short4v*)(xnb + (size_t)row * DIM))[tid] = o;
}

// ---------------------------------------------------------------------------
// Pack wq1|wk1|wv1 -> Wcat bf16 [1536][512]; wout -> woutb bf16 [512][512].
// ---------------------------------------------------------------------------
__global__ __launch_bounds__(256) void convert_w(
    const float* __restrict__ wq1, const float* __restrict__ wk1,
    const float* __restrict__ wv1, const float* __restrict__ wout,
    bf16* __restrict__ Wcat, bf16* __restrict__ woutb)
{
    int i4 = blockIdx.x * 256 + threadIdx.x;    // 0 .. 262143
    int base = i4 * 4;
    int which = base >> 18;                     // 0..3 (256K elements each)
    int e = base & 262143;
    const float* src = which == 0 ? wq1 : which == 1 ? wk1 : which == 2 ? wv1 : wout;
    float4 v = *(const float4*)(src + e);
    bf16* dst = (which < 3) ? (Wcat + ((size_t)which << 18) + e) : (woutb + e);
    short4v o;
    o[0] = f2b(v.x); o[1] = f2b(v.y); o[2] = f2b(v.z); o[3] = f2b(v.w);
    *(short4v*)dst = o;
}

// ---------------------------------------------------------------------------
// C[m, n] = sum_k A[m, k] * W[n, k]   (bf16 in, fp32 out)
// 128x128 tile, BK=64, 4 waves, 16x16x32 MFMA, global_load_lds staging.
// ---------------------------------------------------------------------------
__global__ __launch_bounds__(256) void gemm_bf16_nt(
    const bf16* __restrict__ A, const bf16* __restrict__ W,
    float* __restrict__ C, int N, int K)
{
    __shared__ bf16 As[128 * 64];
    __shared__ bf16 Bs[128 * 64];
    int tid = threadIdx.x;
    int m0 = blockIdx.y * 128, n0 = blockIdx.x * 128;
    int lane = tid & 63;
    int w = tid >> 6;
    int wm = (w >> 1) * 64, wn = (w & 1) * 64;
    int l15 = lane & 15, l4 = lane >> 4;
    f32x4 acc[4][4] = {};
    for (int k0 = 0; k0 < K; k0 += 64) {
        __syncthreads();
        #pragma unroll
        for (int it = 0; it < 4; it++) {
            int s = it * 256 + tid;
            int row = s >> 3, cs = s & 7;
            gload_lds16(A + (size_t)(m0 + row) * K + k0 + cs * 8, As + s * 8);
            gload_lds16(W + (size_t)(n0 + row) * K + k0 + cs * 8, Bs + s * 8);
        }
        __syncthreads();
        #pragma unroll
        for (int kk = 0; kk < 64; kk += 32) {
            short8 af[4], bfr[4];
            #pragma unroll
            for (int m = 0; m < 4; m++)
                af[m] = *(const short8*)(As + (wm + m * 16 + l15) * 64 + kk + l4 * 8);
            #pragma unroll
            for (int n = 0; n < 4; n++)
                bfr[n] = *(const short8*)(Bs + (wn + n * 16 + l15) * 64 + kk + l4 * 8);
            #pragma unroll
            for (int m = 0; m < 4; m++)
                #pragma unroll
                for (int n = 0; n < 4; n++)
                    acc[m][n] = __builtin_amdgcn_mfma_f32_16x16x32_bf16(
                        af[m], bfr[n], acc[m][n], 0, 0, 0);
        }
    }
    #pragma unroll
    for (int m = 0; m < 4; m++)
        #pragma unroll
        for (int n = 0; n < 4; n++) {
            int row = m0 + wm + m * 16 + l4 * 4;
            int col = n0 + wn + n * 16 + l15;
            #pragma unroll
            for (int r = 0; r < 4; r++)
                C[(size_t)(row + r) * N + col] = acc[m][n][r];
        }
}

// ---------------------------------------------------------------------------
// Depthwise causal conv (kernel 3) + head split (+ q scale), bf16 output.
// Reads ycat fp32 [4096][1536]; dst layout [b,h,n,d] bf16.
// ---------------------------------------------------------------------------
__global__ __launch_bounds__(256) void dwconv_kernel(
    const float* __restrict__ ycat,
    const float* __restrict__ wqd, const float* __restrict__ wkd, const float* __restrict__ wvd,
    bf16* __restrict__ q, bf16* __restrict__ k, bf16* __restrict__ v)
{
    int which = blockIdx.z;
    const float* wd = which == 0 ? wqd : which == 1 ? wkd : wvd;
    bf16* dst       = which == 0 ? q   : which == 1 ? k   : v;
    float scale     = which == 0 ? 0.125f : 1.0f;   // DH^-0.5 = 1/8
    int idx = blockIdx.x * 256 + threadIdx.x;       // 0 .. NTOK*DIM-1
    int e = idx & (DIM - 1);
    int t = idx >> 9;
    int n = t & (NSEQ - 1);
    const float* y = ycat + which * DIM;
    float y0 = y[(size_t)t * NPROJ + e];
    float y1 = (n >= 1) ? y[(size_t)(t - 1) * NPROJ + e] : 0.0f;
    float y2 = (n >= 2) ? y[(size_t)(t - 2) * NPROJ + e] : 0.0f;
    float w0 = wd[e * 3 + 0], w1 = wd[e * 3 + 1], w2 = wd[e * 3 + 2];
    float r = (w0 * y2 + w1 * y1 + w2 * y0) * scale;
    int b = t >> 11;
    int h = e >> 6, d = e & 63;
    dst[(((size_t)(b * HEADS + h)) * NSEQ + n) * DH + d] = __float2bfloat16(r);
}

// ---------------------------------------------------------------------------
// V transpose: v[bh][n][d] -> vT[bh][d][n]  (bf16). 64x64 tiles via LDS.
// ---------------------------------------------------------------------------
__global__ __launch_bounds__(256) void vtrans_kernel(
    const bf16* __restrict__ v, bf16* __restrict__ vT)
{
    __shared__ unsigned short L[64][72];
    int bh = blockIdx.y;
    int n0 = blockIdx.x * 64;
    int tid = threadIdx.x;
    const unsigned short* src = (const unsigned short*)v + ((size_t)bh * NSEQ + n0) * DH;
    #pragma unroll
    for (int it = 0; it < 2; it++) {
        int idx = it * 256 + tid;
        int r = idx >> 3, c = (idx & 7) * 8;
        *(short8*)&L[r][c] = *(const short8*)(src + (size_t)r * DH + c);
    }
    __syncthreads();
    unsigned short* dst = (unsigned short*)vT + (size_t)bh * DH * NSEQ + n0;
    #pragma unroll
    for (int it = 0; it < 2; it++) {
        int idx = it * 256 + tid;
        int d = idx >> 3, c8 = (idx & 7) * 8;
        short8 o;
        #pragma unroll
        for (int t = 0; t < 8; t++) o[t] = (short)L[c8 + t][d];
        *(short8*)(dst + (size_t)d * NSEQ + c8) = o;
    }
}

// ---------------------------------------------------------------------------
// MFMA flash attention, 4-way key-parity split, register double-buffer.
// Writes unnormalized partials po[s][bh][row][d], pl[s][bh][row].
// ---------------------------------------------------------------------------
struct KV { short8 kf[4]; short8 v0[2]; short8 v1[2]; };

__device__ __forceinline__ KV load_kv(
    const bf16* __restrict__ Kb, const unsigned short* __restrict__ vt,
    int j0, int il, int hi)
{
    KV r;
    const short8* krow = (const short8*)(Kb + (size_t)(j0 + il) * DH);
    #pragma unroll
    for (int c = 0; c < 4; c++) r.kf[c] = krow[2 * c + hi];
    #pragma unroll
    for (int jc = 0; jc < 2; jc++) {
        r.v0[jc] = *(const short8*)(vt + (size_t)il * NSEQ + j0 + jc * 16 + hi * 8);
        r.v1[jc] = *(const short8*)(vt + (size_t)(32 + il) * NSEQ + j0 + jc * 16 + hi * 8);
    }
    return r;
}

template<bool MASKED>
__device__ __forceinline__ void attn_step(
    const KV& kv, int j0, int il, int hi, int i_global,
    const short8* qf, const float* bconst, float slope2,
    f32x16& o0, f32x16& o1, float& lsum)
{
    f32x16 st = {};
    #pragma unroll
    for (int c = 0; c < 4; c++)
        st = __builtin_amdgcn_mfma_f32_32x32x16_bf16(kv.kf[c], qf[c], st, 0, 0, 0);
    float sdb = slope2 * (float)(j0 - i_global);
    float p[16];
    #pragma unroll
    for (int r = 0; r < 16; r++) {
        float e = fmaf(st[r], 1.4426950408889634f, sdb + bconst[r]);
        float pr = exp2f(e);
        if (MASKED) {
            int jl = (r & 3) + 8 * (r >> 2) + 4 * hi;
            pr = (jl <= il) ? pr : 0.0f;
        }
        p[r] = pr;
        lsum += pr;
    }
    unsigned w[8];
    #pragma unroll
    for (int g = 0; g < 4; g++) {
        asm("v_cvt_pk_bf16_f32 %0, %1, %2" : "=v"(w[2*g])   : "v"(p[4*g]),   "v"(p[4*g+1]));
        asm("v_cvt_pk_bf16_f32 %0, %1, %2" : "=v"(w[2*g+1]) : "v"(p[4*g+2]), "v"(p[4*g+3]));
    }
    #pragma unroll
    for (int jc = 0; jc < 2; jc++) {
        unsigned x0 = w[4*jc], x1 = w[4*jc+1], y0 = w[4*jc+2], y1 = w[4*jc+3];
        asm("v_permlane32_swap_b32 %0, %1" : "+v"(x0), "+v"(y0));
        asm("v_permlane32_swap_b32 %0, %1" : "+v"(x1), "+v"(y1));
        union { unsigned u[4]; short8 s; } pa;
        pa.u[0] = x0; pa.u[1] = x1; pa.u[2] = y0; pa.u[3] = y1;
        o0 = __builtin_amdgcn_mfma_f32_32x32x16_bf16(pa.s, kv.v0[jc], o0, 0, 0, 0);
        o1 = __builtin_amdgcn_mfma_f32_32x32x16_bf16(pa.s, kv.v1[jc], o1, 0, 0, 0);
    }
}

__global__ __launch_bounds__(64) void attn_mfma(
    const bf16* __restrict__ Q, const bf16* __restrict__ K,
    const bf16* __restrict__ VT, float* __restrict__ po, float* __restrict__ pl)
{
    int bh = blockIdx.y;
    int sp = blockIdx.z;                            // key-tile parity 0..3
    int h = bh & (HEADS - 1);
    int ti = (blockIdx.x + 13 * blockIdx.y) & 63;
    int i0 = ti * 32;
    int lane = threadIdx.x;
    int il = lane & 31, hi = lane >> 5;
    int i_global = i0 + il;
    float slope2 = exp2f(-(float)(h + 1)) * 1.4426950408889634f;
    float bconst[16];
    #pragma unroll
    for (int r = 0; r < 16; r++) {
        int jl = (r & 3) + 8 * (r >> 2) + 4 * hi;
        bconst[r] = slope2 * (float)jl;
    }
    const bf16* Qb = Q + (size_t)bh * NSEQ * DH;
    const bf16* Kb = K + (size_t)bh * NSEQ * DH;
    const unsigned short* vt = (const unsigned short*)(VT + (size_t)bh * DH * NSEQ);
    short8 qf[4];
    const short8* qrow = (const short8*)(Qb + (size_t)(i0 + il) * DH);
    #pragma unroll
    for (int c = 0; c < 4; c++) qf[c] = qrow[2 * c + hi];
    f32x16 o0 = {}, o1 = {};
    float lsum = 0.0f;
    if (sp <= ti) {
        KV cur = load_kv(Kb, vt, sp * 32, il, hi);
        for (int kt = sp; kt <= ti; kt += 4) {
            KV nxt;
            bool more = (kt + 4) <= ti;
            if (more) nxt = load_kv(Kb, vt, (kt + 4) * 32, il, hi);
            if (kt == ti)
                attn_step<true >(cur, kt * 32, il, hi, i_global, qf, bconst, slope2, o0, o1, lsum);
            else
                attn_step<false>(cur, kt * 32, il, hi, i_global, qf, bconst, slope2, o0, o1, lsum);
            if (more) cur = nxt;
        }
    }
    float ltot = lsum + __shfl_xor(lsum, 32);
    size_t pbase = ((size_t)sp * (BATCH * HEADS) + bh) * NSEQ + i0;
    if (hi == 0) pl[pbase + il] = ltot;
    float* pop = po + pbase * DH;
    #pragma unroll
    for (int r = 0; r < 16; r++) {
        int irow = (r & 3) + 8 * (r >> 2) + 4 * hi;
        pop[(size_t)irow * DH + il]      = o0[r];
        pop[(size_t)irow * DH + 32 + il] = o1[r];
    }
}

// ---------------------------------------------------------------------------
// Merge 4 splits; write attn output bf16 as [b, n, h*64+d].
// ---------------------------------------------------------------------------
__global__ __launch_bounds__(256) void merge_kernel(
    const float* __restrict__ pl, const float* __restrict__ po,
    bf16* __restrict__ attnb)
{
    int idx = blockIdx.x * 256 + threadIdx.x;   // 0 .. 16*2048*64-1
    int d = idx & 63;
    int rbh = idx >> 6;                         // bh*2048 + n
    int n  = rbh & (NSEQ - 1);
    int bh = rbh >> 11;
    const size_t S = (size_t)(BATCH * HEADS) * NSEQ;  // 32768
    float l = 0.0f, o = 0.0f;
    #pragma unroll
    for (int s = 0; s < 4; s++) {
        l += pl[(size_t)s * S + rbh];
        o += po[((size_t)s * S + rbh) * DH + d];
    }
    int b = bh >> 3, h = bh & 7;
    attnb[((size_t)(b * NSEQ + n)) * DIM + h * DH + d] = __float2bfloat16(o / l);
}

// ---------------------------------------------------------------------------
extern "C" void kernel_launch(void* const* d_in, const int* in_sizes, int n_in,
                              void* d_out, int out_size, void* d_ws, size_t ws_size,
                              hipStream_t stream)
{
    (void)in_sizes; (void)n_in; (void)out_size; (void)ws_size;
    const float* x     = (const float*)d_in[0];
    const float* gamma = (const float*)d_in[1];
    const float* beta  = (const float*)d_in[2];
    const float* wq1   = (const float*)d_in[3];
    const float* wqd   = (const float*)d_in[4];
    const float* wk1   = (const float*)d_in[5];
    const float* wkd   = (const float*)d_in[6];
    const float* wv1   = (const float*)d_in[7];
    const float* wvd   = (const float*)d_in[8];
    const float* wout  = (const float*)d_in[9];
    float* out = (float*)d_out;
    char* base = (char*)d_ws;

    const size_t MB = 1 << 20;
    bf16*  xnb   = (bf16*)(base);                 // 4 MB
    bf16*  Wcat  = (bf16*)(base + 4 * MB);        // 1.5 MB
    bf16*  woutb = (bf16*)(base + 6 * MB);        // 0.5 MB
    bf16*  qb    = (bf16*)(base + 7 * MB);        // 4 MB
    bf16*  kb    = (bf16*)(base + 11 * MB);       // 4 MB
    bf16*  vb    = (bf16*)(base + 15 * MB);       // 4 MB
    bf16*  vtb   = (bf16*)(base + 19 * MB);       // 4 MB
    bf16*  attnb = (bf16*)(base + 23 * MB);       // 4 MB
    float* pl    = (float*)(base + 27 * MB);      // 0.5 MB
    float* ycat  = (float*)(base + 32 * MB);      // 24 MB (dead after dwconv)
    float* po    = (float*)(base + 32 * MB);      // 32 MB (overlaps ycat)

    ln_kernel<<<NTOK, 128, 0, stream>>>(x, gamma, beta, xnb);
    convert_w<<<1024, 256, 0, stream>>>(wq1, wk1, wv1, wout, Wcat, woutb);
    gemm_bf16_nt<<<dim3(NPROJ / 128, NTOK / 128), 256, 0, stream>>>(
        xnb, Wcat, ycat, NPROJ, DIM);
    dwconv_kernel<<<dim3(NTOK * DIM / 256, 1, 3), 256, 0, stream>>>(
        ycat, wqd, wkd, wvd, qb, kb, vb);
    vtrans_kernel<<<dim3(NSEQ / 64, BATCH * HEADS), 256, 0, stream>>>(vb, vtb);
    attn_mfma<<<dim3(64, BATCH * HEADS, 4), 64, 0, stream>>>(qb, kb, vtb, po, pl);
    merge_kernel<<<(BATCH * HEADS * NSEQ * DH) / 256, 256, 0, stream>>>(pl, po, attnb);
    gemm_bf16_nt<<<dim3(DIM / 128, NTOK / 128), 256, 0, stream>>>(
        attnb, woutb, out, DIM, DIM);
}

// Round 5
// 178.999 us; speedup vs baseline: 3.9631x; 1.0064x over previous
//
#include <hip/hip_runtime.h>
#include <hip/hip_bf16.h>
#include <math.h>

#define BATCH 2
#define NSEQ 2048
#define DIM 512
#define HEADS 8
#define DH 64
#define NTOK (BATCH * NSEQ)          // 4096
#define NPROJ (3 * DIM)              // 1536

typedef short short8 __attribute__((ext_vector_type(8)));   // 8 bf16 (4 VGPR)
typedef short short4v __attribute__((ext_vector_type(4)));
typedef float f32x4 __attribute__((ext_vector_type(4)));
typedef float f32x16 __attribute__((ext_vector_type(16)));
typedef __hip_bfloat16 bf16;

static __device__ __forceinline__ short f2b(float f) {
    __hip_bfloat16 h = __float2bfloat16(f);
    return *(short*)&h;
}

static __device__ __forceinline__ void gload_lds16(const void* g, void* l) {
    __builtin_amdgcn_global_load_lds(
        (const __attribute__((address_space(1))) unsigned int*)g,
        (__attribute__((address_space(3))) unsigned int*)l, 16, 0, 0);
}

// ---------------------------------------------------------------------------
// LayerNorm over last dim (512), bf16 output. One block of 128 threads per row.
// ---------------------------------------------------------------------------
__global__ __launch_bounds__(128) void ln_kernel(
    const float* __restrict__ x, const float* __restrict__ gamma,
    const float* __restrict__ beta, bf16* __restrict__ xnb)
{
    int row = blockIdx.x;
    int tid = threadIdx.x;
    float4 v = ((const float4*)(x + (size_t)row * DIM))[tid];
    float s  = v.x + v.y + v.z + v.w;
    float s2 = v.x*v.x + v.y*v.y + v.z*v.z + v.w*v.w;
    #pragma unroll
    for (int off = 32; off > 0; off >>= 1) {
        s  += __shfl_down(s,  off);
        s2 += __shfl_down(s2, off);
    }
    __shared__ float red[4];
    if ((tid & 63) == 0) { red[(tid >> 6) * 2] = s; red[(tid >> 6) * 2 + 1] = s2; }
    __syncthreads();
    float S  = red[0] + red[2];
    float S2 = red[1] + red[3];
    float mu  = S * (1.0f / DIM);
    float var = S2 * (1.0f / DIM) - mu * mu;
    float inv = rsqrtf(var + 1e-5f);
    float4 g  = ((const float4*)gamma)[tid];
    float4 be = ((const float4*)beta)[tid];
    short4v o;
    o[0] = f2b((v.x - mu) * inv * g.x + be.x);
    o[1] = f2b((v.y - mu) * inv * g.y + be.y);
    o[2] = f2b((v.z - mu) * inv * g.z + be.z);
    o[3] = f2b((v.w - mu) * inv * g.w + be.w);
    ((short4v*)(xnb + (size_t)row * DIM))[tid] = o;
}

// ---------------------------------------------------------------------------
// Pack wq1|wk1|wv1 -> Wcat bf16 [1536][512]; wout -> woutb bf16 [512][512].
// ---------------------------------------------------------------------------
__global__ __launch_bounds__(256) void convert_w(
    const float* __restrict__ wq1, const float* __restrict__ wk1,
    const float* __restrict__ wv1, const float* __restrict__ wout,
    bf16* __restrict__ Wcat, bf16* __restrict__ woutb)
{
    int i4 = blockIdx.x * 256 + threadIdx.x;    // 0 .. 262143
    int base = i4 * 4;
    int which = base >> 18;                     // 0..3 (256K elements each)
    int e = base & 262143;
    const float* src = which == 0 ? wq1 : which == 1 ? wk1 : which == 2 ? wv1 : wout;
    float4 v = *(const float4*)(src + e);
    bf16* dst = (which < 3) ? (Wcat + ((size_t)which << 18) + e) : (woutb + e);
    short4v o;
    o[0] = f2b(v.x); o[1] = f2b(v.y); o[2] = f2b(v.z); o[3] = f2b(v.w);
    *(short4v*)dst = o;
}

// ---------------------------------------------------------------------------
// C[m, n] = sum_k A[m, k] * W[n, k]   (bf16 in, fp32 out)
// 128x128 tile, BK=64, 4 waves, 16x16x32 MFMA, global_load_lds staging.
// ---------------------------------------------------------------------------
__global__ __launch_bounds__(256) void gemm_bf16_nt(
    const bf16* __restrict__ A, const bf16* __restrict__ W,
    float* __restrict__ C, int N, int K)
{
    __shared__ bf16 As[128 * 64];
    __shared__ bf16 Bs[128 * 64];
    int tid = threadIdx.x;
    int m0 = blockIdx.y * 128, n0 = blockIdx.x * 128;
    int lane = tid & 63;
    int w = tid >> 6;
    int wm = (w >> 1) * 64, wn = (w & 1) * 64;
    int l15 = lane & 15, l4 = lane >> 4;
    f32x4 acc[4][4] = {};
    for (int k0 = 0; k0 < K; k0 += 64) {
        __syncthreads();
        #pragma unroll
        for (int it = 0; it < 4; it++) {
            int s = it * 256 + tid;
            int row = s >> 3, cs = s & 7;
            gload_lds16(A + (size_t)(m0 + row) * K + k0 + cs * 8, As + s * 8);
            gload_lds16(W + (size_t)(n0 + row) * K + k0 + cs * 8, Bs + s * 8);
        }
        __syncthreads();
        #pragma unroll
        for (int kk = 0; kk < 64; kk += 32) {
            short8 af[4], bfr[4];
            #pragma unroll
            for (int m = 0; m < 4; m++)
                af[m] = *(const short8*)(As + (wm + m * 16 + l15) * 64 + kk + l4 * 8);
            #pragma unroll
            for (int n = 0; n < 4; n++)
                bfr[n] = *(const short8*)(Bs + (wn + n * 16 + l15) * 64 + kk + l4 * 8);
            #pragma unroll
            for (int m = 0; m < 4; m++)
                #pragma unroll
                for (int n = 0; n < 4; n++)
                    acc[m][n] = __builtin_amdgcn_mfma_f32_16x16x32_bf16(
                        af[m], bfr[n], acc[m][n], 0, 0, 0);
        }
    }
    #pragma unroll
    for (int m = 0; m < 4; m++)
        #pragma unroll
        for (int n = 0; n < 4; n++) {
            int row = m0 + wm + m * 16 + l4 * 4;
            int col = n0 + wn + n * 16 + l15;
            #pragma unroll
            for (int r = 0; r < 4; r++)
                C[(size_t)(row + r) * N + col] = acc[m][n][r];
        }
}

// ---------------------------------------------------------------------------
// Depthwise causal conv (kernel 3) + head split (+ q scale), bf16 output.
// Vectorized: 4 channels per thread. Reads ycat fp32 [4096][1536].
// ---------------------------------------------------------------------------
__global__ __launch_bounds__(256) void dwconv_kernel(
    const float* __restrict__ ycat,
    const float* __restrict__ wqd, const float* __restrict__ wkd, const float* __restrict__ wvd,
    bf16* __restrict__ q, bf16* __restrict__ k, bf16* __restrict__ v)
{
    int which = blockIdx.z;
    const float* wd = which == 0 ? wqd : which == 1 ? wkd : wvd;
    bf16* dst       = which == 0 ? q   : which == 1 ? k   : v;
    float scale     = which == 0 ? 0.125f : 1.0f;   // DH^-0.5 = 1/8
    int idx = blockIdx.x * 256 + threadIdx.x;       // 0 .. NTOK*128-1
    int e4 = idx & 127;
    int t  = idx >> 7;
    int n  = t & (NSEQ - 1);
    int e  = e4 * 4;
    const float* y = ycat + (size_t)t * NPROJ + which * DIM + e;
    float4 zero = make_float4(0, 0, 0, 0);
    float4 y0 = *(const float4*)y;
    float4 y1 = (n >= 1) ? *(const float4*)(y - NPROJ) : zero;
    float4 y2 = (n >= 2) ? *(const float4*)(y - 2 * NPROJ) : zero;
    const float4* wp = (const float4*)(wd + e * 3);
    float4 wA = wp[0], wB = wp[1], wC = wp[2];
    short4v o;
    o[0] = f2b((wA.x * y2.x + wA.y * y1.x + wA.z * y0.x) * scale);
    o[1] = f2b((wA.w * y2.y + wB.x * y1.y + wB.y * y0.y) * scale);
    o[2] = f2b((wB.z * y2.z + wB.w * y1.z + wC.x * y0.z) * scale);
    o[3] = f2b((wC.y * y2.w + wC.z * y1.w + wC.w * y0.w) * scale);
    int b = t >> 11;
    int h = e >> 6, d = e & 63;
    *(short4v*)(dst + (((size_t)(b * HEADS + h)) * NSEQ + n) * DH + d) = o;
}

// ---------------------------------------------------------------------------
// V transpose: v[bh][n][d] -> vT[bh][d][n]  (bf16). 64x64 tiles via LDS.
// ---------------------------------------------------------------------------
__global__ __launch_bounds__(256) void vtrans_kernel(
    const bf16* __restrict__ v, bf16* __restrict__ vT)
{
    __shared__ unsigned short L[64][72];
    int bh = blockIdx.y;
    int n0 = blockIdx.x * 64;
    int tid = threadIdx.x;
    const unsigned short* src = (const unsigned short*)v + ((size_t)bh * NSEQ + n0) * DH;
    #pragma unroll
    for (int it = 0; it < 2; it++) {
        int idx = it * 256 + tid;
        int r = idx >> 3, c = (idx & 7) * 8;
        *(short8*)&L[r][c] = *(const short8*)(src + (size_t)r * DH + c);
    }
    __syncthreads();
    unsigned short* dst = (unsigned short*)vT + (size_t)bh * DH * NSEQ + n0;
    #pragma unroll
    for (int it = 0; it < 2; it++) {
        int idx = it * 256 + tid;
        int d = idx >> 3, c8 = (idx & 7) * 8;
        short8 o;
        #pragma unroll
        for (int t = 0; t < 8; t++) o[t] = (short)L[c8 + t][d];
        *(short8*)(dst + (size_t)d * NSEQ + c8) = o;
    }
}

// ---------------------------------------------------------------------------
// MFMA flash attention, dual query-tile waves + 4-way key split.
// Wave owns tiles (2t, 2t+1): each KV load feeds 16 MFMA + 2 softmaxes.
// Heavy-first dispatch: t = 31 - blockIdx.x.
// ---------------------------------------------------------------------------
struct Kf { short8 k[4]; };
struct Vf { short8 v0[2]; short8 v1[2]; };

__device__ __forceinline__ Kf load_k(const bf16* __restrict__ Kb, int j0, int il, int hi) {
    Kf r;
    const short8* krow = (const short8*)(Kb + (size_t)(j0 + il) * DH);
    #pragma unroll
    for (int c = 0; c < 4; c++) r.k[c] = krow[2 * c + hi];
    return r;
}

__device__ __forceinline__ Vf load_v(const unsigned short* __restrict__ vt, int j0, int il, int hi) {
    Vf r;
    #pragma unroll
    for (int jc = 0; jc < 2; jc++) {
        r.v0[jc] = *(const short8*)(vt + (size_t)il * NSEQ + j0 + jc * 16 + hi * 8);
        r.v1[jc] = *(const short8*)(vt + (size_t)(32 + il) * NSEQ + j0 + jc * 16 + hi * 8);
    }
    return r;
}

template<bool MASKED>
__device__ __forceinline__ void tile_step(
    const Kf& kf, const Vf& vf, const short8* qf,
    int j0, int il, int hi, int i_global,
    const float* bconst, float slope2,
    f32x16& o0, f32x16& o1, float& lsum)
{
    f32x16 st = {};
    #pragma unroll
    for (int c = 0; c < 4; c++)
        st = __builtin_amdgcn_mfma_f32_32x32x16_bf16(kf.k[c], qf[c], st, 0, 0, 0);
    float sdb = slope2 * (float)(j0 - i_global);
    float p[16];
    #pragma unroll
    for (int r = 0; r < 16; r++) {
        float e = fmaf(st[r], 1.4426950408889634f, sdb + bconst[r]);
        float pr = exp2f(e);
        if (MASKED) {
            int jl = (r & 3) + 8 * (r >> 2) + 4 * hi;
            pr = (jl <= il) ? pr : 0.0f;
        }
        p[r] = pr;
        lsum += pr;
    }
    unsigned w[8];
    #pragma unroll
    for (int g = 0; g < 4; g++) {
        asm("v_cvt_pk_bf16_f32 %0, %1, %2" : "=v"(w[2*g])   : "v"(p[4*g]),   "v"(p[4*g+1]));
        asm("v_cvt_pk_bf16_f32 %0, %1, %2" : "=v"(w[2*g+1]) : "v"(p[4*g+2]), "v"(p[4*g+3]));
    }
    #pragma unroll
    for (int jc = 0; jc < 2; jc++) {
        unsigned x0 = w[4*jc], x1 = w[4*jc+1], y0 = w[4*jc+2], y1 = w[4*jc+3];
        asm("v_permlane32_swap_b32 %0, %1" : "+v"(x0), "+v"(y0));
        asm("v_permlane32_swap_b32 %0, %1" : "+v"(x1), "+v"(y1));
        union { unsigned u[4]; short8 s; } pa;
        pa.u[0] = x0; pa.u[1] = x1; pa.u[2] = y0; pa.u[3] = y1;
        o0 = __builtin_amdgcn_mfma_f32_32x32x16_bf16(pa.s, vf.v0[jc], o0, 0, 0, 0);
        o1 = __builtin_amdgcn_mfma_f32_32x32x16_bf16(pa.s, vf.v1[jc], o1, 0, 0, 0);
    }
}

__device__ __forceinline__ void write_tile(
    float* __restrict__ po, float* __restrict__ pl,
    int sp, int bh, int i0, int il, int hi,
    const f32x16& o0, const f32x16& o1, float lsum)
{
    float ltot = lsum + __shfl_xor(lsum, 32);
    size_t pbase = ((size_t)sp * (BATCH * HEADS) + bh) * NSEQ + i0;
    if (hi == 0) pl[pbase + il] = ltot;
    float* pop = po + pbase * DH;
    #pragma unroll
    for (int r = 0; r < 16; r++) {
        int irow = (r & 3) + 8 * (r >> 2) + 4 * hi;
        pop[(size_t)irow * DH + il]      = o0[r];
        pop[(size_t)irow * DH + 32 + il] = o1[r];
    }
}

__global__ __launch_bounds__(64) void attn_mfma(
    const bf16* __restrict__ Q, const bf16* __restrict__ K,
    const bf16* __restrict__ VT, float* __restrict__ po, float* __restrict__ pl)
{
    int t  = 31 - blockIdx.x;                       // heavy tiles dispatch first
    int bh = blockIdx.y;
    int sp = blockIdx.z;                            // key-tile residue 0..3
    int h = bh & (HEADS - 1);
    int tiA = 2 * t, tiB = 2 * t + 1;
    int i0A = tiA * 32, i0B = i0A + 32;
    int lane = threadIdx.x;
    int il = lane & 31, hi = lane >> 5;
    float slope2 = exp2f(-(float)(h + 1)) * 1.4426950408889634f;
    float bconst[16];
    #pragma unroll
    for (int r = 0; r < 16; r++) {
        int jl = (r & 3) + 8 * (r >> 2) + 4 * hi;
        bconst[r] = slope2 * (float)jl;
    }
    const bf16* Qb = Q + (size_t)bh * NSEQ * DH;
    const bf16* Kb = K + (size_t)bh * NSEQ * DH;
    const unsigned short* vt = (const unsigned short*)(VT + (size_t)bh * DH * NSEQ);
    short8 qfA[4], qfB[4];
    {
        const short8* qra = (const short8*)(Qb + (size_t)(i0A + il) * DH);
        const short8* qrb = (const short8*)(Qb + (size_t)(i0B + il) * DH);
        #pragma unroll
        for (int c = 0; c < 4; c++) { qfA[c] = qra[2 * c + hi]; qfB[c] = qrb[2 * c + hi]; }
    }
    f32x16 oA0 = {}, oA1 = {}, oB0 = {}, oB1 = {};
    float lsA = 0.0f, lsB = 0.0f;

    Kf kcur = load_k(Kb, sp * 32, il, hi);          // rows <= 127, always valid
    for (int kt = sp; kt <= tiB; kt += 4) {
        int j0 = kt * 32;
        Vf vf = load_v(vt, j0, il, hi);
        int jn = (kt + 4 <= tiB) ? (kt + 4) * 32 : j0;
        Kf knxt = load_k(Kb, jn, il, hi);
        if (kt < tiA) {
            tile_step<false>(kcur, vf, qfA, j0, il, hi, i0A + il, bconst, slope2, oA0, oA1, lsA);
            tile_step<false>(kcur, vf, qfB, j0, il, hi, i0B + il, bconst, slope2, oB0, oB1, lsB);
        } else if (kt == tiA) {
            tile_step<true >(kcur, vf, qfA, j0, il, hi, i0A + il, bconst, slope2, oA0, oA1, lsA);
            tile_step<false>(kcur, vf, qfB, j0, il, hi, i0B + il, bconst, slope2, oB0, oB1, lsB);
        } else {    // kt == tiB
            tile_step<true >(kcur, vf, qfB, j0, il, hi, i0B + il, bconst, slope2, oB0, oB1, lsB);
        }
        kcur = knxt;
    }
    write_tile(po, pl, sp, bh, i0A, il, hi, oA0, oA1, lsA);
    write_tile(po, pl, sp, bh, i0B, il, hi, oB0, oB1, lsB);
}

// ---------------------------------------------------------------------------
// Merge 4 splits (vectorized, 4 d's per thread); write bf16 [b, n, h*64+d].
// ---------------------------------------------------------------------------
__global__ __launch_bounds__(256) void merge_kernel(
    const float* __restrict__ pl, const float* __restrict__ po,
    bf16* __restrict__ attnb)
{
    int idx = blockIdx.x * 256 + threadIdx.x;   // 0 .. 16*2048*16-1
    int d = (idx & 15) * 4;
    int rbh = idx >> 4;                         // bh*2048 + n
    int n  = rbh & (NSEQ - 1);
    int bh = rbh >> 11;
    const size_t S = (size_t)(BATCH * HEADS) * NSEQ;  // 32768
    float l = 0.0f;
    float ox = 0, oy = 0, oz = 0, ow = 0;
    #pragma unroll
    for (int s = 0; s < 4; s++) {
        l += pl[(size_t)s * S + rbh];
        float4 p = *(const float4*)(po + ((size_t)s * S + rbh) * DH + d);
        ox += p.x; oy += p.y; oz += p.z; ow += p.w;
    }
    float inv = 1.0f / l;
    int b = bh >> 3, h = bh & 7;
    short4v o;
    o[0] = f2b(ox * inv); o[1] = f2b(oy * inv);
    o[2] = f2b(oz * inv); o[3] = f2b(ow * inv);
    *(short4v*)(attnb + ((size_t)(b * NSEQ + n)) * DIM + h * DH + d) = o;
}

// ---------------------------------------------------------------------------
extern "C" void kernel_launch(void* const* d_in, const int* in_sizes, int n_in,
                              void* d_out, int out_size, void* d_ws, size_t ws_size,
                              hipStream_t stream)
{
    (void)in_sizes; (void)n_in; (void)out_size; (void)ws_size;
    const float* x     = (const float*)d_in[0];
    const float* gamma = (const float*)d_in[1];
    const float* beta  = (const float*)d_in[2];
    const float* wq1   = (const float*)d_in[3];
    const float* wqd   = (const float*)d_in[4];
    const float* wk1   = (const float*)d_in[5];
    const float* wkd   = (const float*)d_in[6];
    const float* wv1   = (const float*)d_in[7];
    const float* wvd   = (const float*)d_in[8];
    const float* wout  = (const float*)d_in[9];
    float* out = (float*)d_out;
    char* base = (char*)d_ws;

    const size_t MB = 1 << 20;
    bf16*  xnb   = (bf16*)(base);                 // 4 MB
    bf16*  Wcat  = (bf16*)(base + 4 * MB);        // 1.5 MB
    bf16*  woutb = (bf16*)(base + 6 * MB);        // 0.5 MB
    bf16*  qb    = (bf16*)(base + 7 * MB);        // 4 MB
    bf16*  kb    = (bf16*)(base + 11 * MB);       // 4 MB
    bf16*  vb    = (bf16*)(base + 15 * MB);       // 4 MB
    bf16*  vtb   = (bf16*)(base + 19 * MB);       // 4 MB
    bf16*  attnb = (bf16*)(base + 23 * MB);       // 4 MB
    float* pl    = (float*)(base + 27 * MB);      // 0.5 MB
    float* ycat  = (float*)(base + 32 * MB);      // 24 MB (dead after dwconv)
    float* po    = (float*)(base + 32 * MB);      // 32 MB (overlaps ycat)

    ln_kernel<<<NTOK, 128, 0, stream>>>(x, gamma, beta, xnb);
    convert_w<<<1024, 256, 0, stream>>>(wq1, wk1, wv1, wout, Wcat, woutb);
    gemm_bf16_nt<<<dim3(NPROJ / 128, NTOK / 128), 256, 0, stream>>>(
        xnb, Wcat, ycat, NPROJ, DIM);
    dwconv_kernel<<<dim3(NTOK * 128 / 256, 1, 3), 256, 0, stream>>>(
        ycat, wqd, wkd, wvd, qb, kb, vb);
    vtrans_kernel<<<dim3(NSEQ / 64, BATCH * HEADS), 256, 0, stream>>>(vb, vtb);
    attn_mfma<<<dim3(32, BATCH * HEADS, 4), 64, 0, stream>>>(qb, kb, vtb, po, pl);
    merge_kernel<<<(BATCH * HEADS * NSEQ * 16) / 256, 256, 0, stream>>>(pl, po, attnb);
    gemm_bf16_nt<<<dim3(DIM / 128, NTOK / 128), 256, 0, stream>>>(
        attnb, woutb, out, DIM, DIM);
}

// Round 6
// 164.905 us; speedup vs baseline: 4.3018x; 1.0855x over previous
//
#include <hip/hip_runtime.h>
#include <hip/hip_bf16.h>
#include <math.h>

#define BATCH 2
#define NSEQ 2048
#define DIM 512
#define HEADS 8
#define DH 64
#define NTOK (BATCH * NSEQ)          // 4096
#define NPROJ (3 * DIM)              // 1536

typedef short short8 __attribute__((ext_vector_type(8)));   // 8 bf16 (4 VGPR)
typedef short short4v __attribute__((ext_vector_type(4)));
typedef float f32x4 __attribute__((ext_vector_type(4)));
typedef float f32x16 __attribute__((ext_vector_type(16)));
typedef __hip_bfloat16 bf16;

static __device__ __forceinline__ short f2b(float f) {
    __hip_bfloat16 h = __float2bfloat16(f);
    return *(short*)&h;
}

static __device__ __forceinline__ void gload_lds16(const void* g, void* l) {
    __builtin_amdgcn_global_load_lds(
        (const __attribute__((address_space(1))) unsigned int*)g,
        (__attribute__((address_space(3))) unsigned int*)l, 16, 0, 0);
}

// ---------------------------------------------------------------------------
// Fused: LayerNorm (blocks 0..4095, one row each) + weight bf16 pack
// (blocks 4096..6143). 128 threads.
// ---------------------------------------------------------------------------
__global__ __launch_bounds__(128) void ln_convert(
    const float* __restrict__ x, const float* __restrict__ gamma,
    const float* __restrict__ beta, bf16* __restrict__ xnb,
    const float* __restrict__ wq1, const float* __restrict__ wk1,
    const float* __restrict__ wv1, const float* __restrict__ wout,
    bf16* __restrict__ Wcat, bf16* __restrict__ woutb)
{
    if (blockIdx.x < NTOK) {
        int row = blockIdx.x;
        int tid = threadIdx.x;
        float4 v = ((const float4*)(x + (size_t)row * DIM))[tid];
        float s  = v.x + v.y + v.z + v.w;
        float s2 = v.x*v.x + v.y*v.y + v.z*v.z + v.w*v.w;
        #pragma unroll
        for (int off = 32; off > 0; off >>= 1) {
            s  += __shfl_down(s,  off);
            s2 += __shfl_down(s2, off);
        }
        __shared__ float red[4];
        if ((tid & 63) == 0) { red[(tid >> 6) * 2] = s; red[(tid >> 6) * 2 + 1] = s2; }
        __syncthreads();
        float S  = red[0] + red[2];
        float S2 = red[1] + red[3];
        float mu  = S * (1.0f / DIM);
        float var = S2 * (1.0f / DIM) - mu * mu;
        float inv = rsqrtf(var + 1e-5f);
        float4 g  = ((const float4*)gamma)[tid];
        float4 be = ((const float4*)beta)[tid];
        short4v o;
        o[0] = f2b((v.x - mu) * inv * g.x + be.x);
        o[1] = f2b((v.y - mu) * inv * g.y + be.y);
        o[2] = f2b((v.z - mu) * inv * g.z + be.z);
        o[3] = f2b((v.w - mu) * inv * g.w + be.w);
        ((short4v*)(xnb + (size_t)row * DIM))[tid] = o;
    } else {
        int i4 = (blockIdx.x - NTOK) * 128 + threadIdx.x;   // 0 .. 262143
        int base = i4 * 4;
        int which = base >> 18;                 // 0..3 (256K elements each)
        int e = base & 262143;
        const float* src = which == 0 ? wq1 : which == 1 ? wk1 : which == 2 ? wv1 : wout;
        float4 v = *(const float4*)(src + e);
        bf16* dst = (which < 3) ? (Wcat + ((size_t)which << 18) + e) : (woutb + e);
        short4v o;
        o[0] = f2b(v.x); o[1] = f2b(v.y); o[2] = f2b(v.z); o[3] = f2b(v.w);
        *(short4v*)dst = o;
    }
}

// ---------------------------------------------------------------------------
// C[m, n] = sum_k A[m, k] * W[n, k]   (bf16 in, fp32 out)
// 128xBN tile, BK=64, 4 waves, 16x16x32 MFMA, 2-phase double-buffered
// global_load_lds pipeline (issue next tile before computing current).
// ---------------------------------------------------------------------------
template<int BN>
__global__ __launch_bounds__(256) void gemm_bf16_nt(
    const bf16* __restrict__ A, const bf16* __restrict__ W,
    float* __restrict__ C, int N, int K)
{
    constexpr int BITS = BN / 32;            // B-stage iterations (and n-frags)
    __shared__ bf16 As[2][128 * 64];
    __shared__ bf16 Bs[2][BN * 64];
    int tid = threadIdx.x;
    int m0 = blockIdx.y * 128, n0 = blockIdx.x * BN;
    int lane = tid & 63;
    int w = tid >> 6;
    int wm = (w >> 1) * 64, wn = (w & 1) * (BN / 2);
    int l15 = lane & 15, l4 = lane >> 4;
    f32x4 acc[4][BITS] = {};

    auto stage = [&](int b, int k0) {
        #pragma unroll
        for (int it = 0; it < 4; it++) {
            int s = it * 256 + tid;
            int row = s >> 3, cs = s & 7;
            gload_lds16(A + (size_t)(m0 + row) * K + k0 + cs * 8, &As[b][s * 8]);
        }
        #pragma unroll
        for (int it = 0; it < BITS; it++) {
            int s = it * 256 + tid;
            int row = s >> 3, cs = s & 7;
            gload_lds16(W + (size_t)(n0 + row) * K + k0 + cs * 8, &Bs[b][s * 8]);
        }
    };

    int NT = K / 64;
    stage(0, 0);
    __syncthreads();
    for (int t = 0; t < NT; ++t) {
        int cur = t & 1;
        if (t + 1 < NT) stage(cur ^ 1, (t + 1) * 64);   // issue-early: overlaps MFMA below
        #pragma unroll
        for (int kk = 0; kk < 64; kk += 32) {
            short8 af[4], bfr[BITS];
            #pragma unroll
            for (int m = 0; m < 4; m++)
                af[m] = *(const short8*)(&As[cur][(wm + m * 16 + l15) * 64 + kk + l4 * 8]);
            #pragma unroll
            for (int n = 0; n < BITS; n++)
                bfr[n] = *(const short8*)(&Bs[cur][(wn + n * 16 + l15) * 64 + kk + l4 * 8]);
            #pragma unroll
            for (int m = 0; m < 4; m++)
                #pragma unroll
                for (int n = 0; n < BITS; n++)
                    acc[m][n] = __builtin_amdgcn_mfma_f32_16x16x32_bf16(
                        af[m], bfr[n], acc[m][n], 0, 0, 0);
        }
        __syncthreads();   // drains next-tile loads (mostly landed under MFMA)
    }
    #pragma unroll
    for (int m = 0; m < 4; m++)
        #pragma unroll
        for (int n = 0; n < BITS; n++) {
            int row = m0 + wm + m * 16 + l4 * 4;
            int col = n0 + wn + n * 16 + l15;
            #pragma unroll
            for (int r = 0; r < 4; r++)
                C[(size_t)(row + r) * N + col] = acc[m][n][r];
        }
}

// ---------------------------------------------------------------------------
// Depthwise causal conv (kernel 3) + head split (+ q scale), bf16 output.
// Vectorized: 4 channels per thread. Reads ycat fp32 [4096][1536].
// ---------------------------------------------------------------------------
__global__ __launch_bounds__(256) void dwconv_kernel(
    const float* __restrict__ ycat,
    const float* __restrict__ wqd, const float* __restrict__ wkd, const float* __restrict__ wvd,
    bf16* __restrict__ q, bf16* __restrict__ k, bf16* __restrict__ v)
{
    int which = blockIdx.z;
    const float* wd = which == 0 ? wqd : which == 1 ? wkd : wvd;
    bf16* dst       = which == 0 ? q   : which == 1 ? k   : v;
    float scale     = which == 0 ? 0.125f : 1.0f;   // DH^-0.5 = 1/8
    int idx = blockIdx.x * 256 + threadIdx.x;       // 0 .. NTOK*128-1
    int e4 = idx & 127;
    int t  = idx >> 7;
    int n  = t & (NSEQ - 1);
    int e  = e4 * 4;
    const float* y = ycat + (size_t)t * NPROJ + which * DIM + e;
    float4 zero = make_float4(0, 0, 0, 0);
    float4 y0 = *(const float4*)y;
    float4 y1 = (n >= 1) ? *(const float4*)(y - NPROJ) : zero;
    float4 y2 = (n >= 2) ? *(const float4*)(y - 2 * NPROJ) : zero;
    const float4* wp = (const float4*)(wd + e * 3);
    float4 wA = wp[0], wB = wp[1], wC = wp[2];
    short4v o;
    o[0] = f2b((wA.x * y2.x + wA.y * y1.x + wA.z * y0.x) * scale);
    o[1] = f2b((wA.w * y2.y + wB.x * y1.y + wB.y * y0.y) * scale);
    o[2] = f2b((wB.z * y2.z + wB.w * y1.z + wC.x * y0.z) * scale);
    o[3] = f2b((wC.y * y2.w + wC.z * y1.w + wC.w * y0.w) * scale);
    int b = t >> 11;
    int h = e >> 6, d = e & 63;
    *(short4v*)(dst + (((size_t)(b * HEADS + h)) * NSEQ + n) * DH + d) = o;
}

// ---------------------------------------------------------------------------
// V transpose: v[bh][n][d] -> vT[bh][d][n]  (bf16). 64x64 tiles via LDS.
// ---------------------------------------------------------------------------
__global__ __launch_bounds__(256) void vtrans_kernel(
    const bf16* __restrict__ v, bf16* __restrict__ vT)
{
    __shared__ unsigned short L[64][72];
    int bh = blockIdx.y;
    int n0 = blockIdx.x * 64;
    int tid = threadIdx.x;
    const unsigned short* src = (const unsigned short*)v + ((size_t)bh * NSEQ + n0) * DH;
    #pragma unroll
    for (int it = 0; it < 2; it++) {
        int idx = it * 256 + tid;
        int r = idx >> 3, c = (idx & 7) * 8;
        *(short8*)&L[r][c] = *(const short8*)(src + (size_t)r * DH + c);
    }
    __syncthreads();
    unsigned short* dst = (unsigned short*)vT + (size_t)bh * DH * NSEQ + n0;
    #pragma unroll
    for (int it = 0; it < 2; it++) {
        int idx = it * 256 + tid;
        int d = idx >> 3, c8 = (idx & 7) * 8;
        short8 o;
        #pragma unroll
        for (int t = 0; t < 8; t++) o[t] = (short)L[c8 + t][d];
        *(short8*)(dst + (size_t)d * NSEQ + c8) = o;
    }
}

// ---------------------------------------------------------------------------
// MFMA flash attention, dual query-tile waves + 4-way key split + ALiBi
// window cutoff (keys with i-j > 20*2^(h+1) contribute < e^-20 relative).
// ---------------------------------------------------------------------------
struct Kf { short8 k[4]; };
struct Vf { short8 v0[2]; short8 v1[2]; };

__device__ __forceinline__ Kf load_k(const bf16* __restrict__ Kb, int j0, int il, int hi) {
    Kf r;
    const short8* krow = (const short8*)(Kb + (size_t)(j0 + il) * DH);
    #pragma unroll
    for (int c = 0; c < 4; c++) r.k[c] = krow[2 * c + hi];
    return r;
}

__device__ __forceinline__ Vf load_v(const unsigned short* __restrict__ vt, int j0, int il, int hi) {
    Vf r;
    #pragma unroll
    for (int jc = 0; jc < 2; jc++) {
        r.v0[jc] = *(const short8*)(vt + (size_t)il * NSEQ + j0 + jc * 16 + hi * 8);
        r.v1[jc] = *(const short8*)(vt + (size_t)(32 + il) * NSEQ + j0 + jc * 16 + hi * 8);
    }
    return r;
}

template<bool MASKED>
__device__ __forceinline__ void tile_step(
    const Kf& kf, const Vf& vf, const short8* qf,
    int j0, int il, int hi, int i_global,
    const float* bconst, float slope2,
    f32x16& o0, f32x16& o1, float& lsum)
{
    f32x16 st = {};
    #pragma unroll
    for (int c = 0; c < 4; c++)
        st = __builtin_amdgcn_mfma_f32_32x32x16_bf16(kf.k[c], qf[c], st, 0, 0, 0);
    float sdb = slope2 * (float)(j0 - i_global);
    float p[16];
    #pragma unroll
    for (int r = 0; r < 16; r++) {
        float e = fmaf(st[r], 1.4426950408889634f, sdb + bconst[r]);
        float pr = exp2f(e);
        if (MASKED) {
            int jl = (r & 3) + 8 * (r >> 2) + 4 * hi;
            pr = (jl <= il) ? pr : 0.0f;
        }
        p[r] = pr;
        lsum += pr;
    }
    unsigned w[8];
    #pragma unroll
    for (int g = 0; g < 4; g++) {
        asm("v_cvt_pk_bf16_f32 %0, %1, %2" : "=v"(w[2*g])   : "v"(p[4*g]),   "v"(p[4*g+1]));
        asm("v_cvt_pk_bf16_f32 %0, %1, %2" : "=v"(w[2*g+1]) : "v"(p[4*g+2]), "v"(p[4*g+3]));
    }
    #pragma unroll
    for (int jc = 0; jc < 2; jc++) {
        unsigned x0 = w[4*jc], x1 = w[4*jc+1], y0 = w[4*jc+2], y1 = w[4*jc+3];
        asm("v_permlane32_swap_b32 %0, %1" : "+v"(x0), "+v"(y0));
        asm("v_permlane32_swap_b32 %0, %1" : "+v"(x1), "+v"(y1));
        union { unsigned u[4]; short8 s; } pa;
        pa.u[0] = x0; pa.u[1] = x1; pa.u[2] = y0; pa.u[3] = y1;
        o0 = __builtin_amdgcn_mfma_f32_32x32x16_bf16(pa.s, vf.v0[jc], o0, 0, 0, 0);
        o1 = __builtin_amdgcn_mfma_f32_32x32x16_bf16(pa.s, vf.v1[jc], o1, 0, 0, 0);
    }
}

__device__ __forceinline__ void write_tile(
    float* __restrict__ po, float* __restrict__ pl,
    int sp, int bh, int i0, int il, int hi,
    const f32x16& o0, const f32x16& o1, float lsum)
{
    float ltot = lsum + __shfl_xor(lsum, 32);
    size_t pbase = ((size_t)sp * (BATCH * HEADS) + bh) * NSEQ + i0;
    if (hi == 0) pl[pbase + il] = ltot;
    float* pop = po + pbase * DH;
    #pragma unroll
    for (int r = 0; r < 16; r++) {
        int irow = (r & 3) + 8 * (r >> 2) + 4 * hi;
        pop[(size_t)irow * DH + il]      = o0[r];
        pop[(size_t)irow * DH + 32 + il] = o1[r];
    }
}

__global__ __launch_bounds__(64) void attn_mfma(
    const bf16* __restrict__ Q, const bf16* __restrict__ K,
    const bf16* __restrict__ VT, float* __restrict__ po, float* __restrict__ pl)
{
    int t  = 31 - blockIdx.x;                       // heavy tiles dispatch first
    int bh = blockIdx.y;
    int sp = blockIdx.z;                            // key-tile residue 0..3
    int h = bh & (HEADS - 1);
    int tiA = 2 * t, tiB = 2 * t + 1;
    int i0A = tiA * 32, i0B = i0A + 32;
    int lane = threadIdx.x;
    int il = lane & 31, hi = lane >> 5;
    float slope2 = exp2f(-(float)(h + 1)) * 1.4426950408889634f;
    float bconst[16];
    #pragma unroll
    for (int r = 0; r < 16; r++) {
        int jl = (r & 3) + 8 * (r >> 2) + 4 * hi;
        bconst[r] = slope2 * (float)jl;
    }
    const bf16* Qb = Q + (size_t)bh * NSEQ * DH;
    const bf16* Kb = K + (size_t)bh * NSEQ * DH;
    const unsigned short* vt = (const unsigned short*)(VT + (size_t)bh * DH * NSEQ);
    short8 qfA[4], qfB[4];
    {
        const short8* qra = (const short8*)(Qb + (size_t)(i0A + il) * DH);
        const short8* qrb = (const short8*)(Qb + (size_t)(i0B + il) * DH);
        #pragma unroll
        for (int c = 0; c < 4; c++) { qfA[c] = qra[2 * c + hi]; qfB[c] = qrb[2 * c + hi]; }
    }
    f32x16 oA0 = {}, oA1 = {}, oB0 = {}, oB1 = {};
    float lsA = 0.0f, lsB = 0.0f;

    // ALiBi window: keys with (i - j) > Wn are negligible (< e^-20 relative).
    int Wn = 20 << (h + 1);
    int lo = (i0A - Wn) >> 5;                       // first useful kt (floor)
    int kt0 = sp;
    if (lo > sp) kt0 = sp + (((lo - sp) + 3) & ~3); // round up, keep kt0 % 4 == sp

    Kf kcur = load_k(Kb, kt0 * 32, il, hi);         // kt0*32 <= i0A < NSEQ: valid
    for (int kt = kt0; kt <= tiB; kt += 4) {
        int j0 = kt * 32;
        Vf vf = load_v(vt, j0, il, hi);
        int jn = (kt + 4 <= tiB) ? (kt + 4) * 32 : j0;
        Kf knxt = load_k(Kb, jn, il, hi);
        if (kt < tiA) {
            tile_step<false>(kcur, vf, qfA, j0, il, hi, i0A + il, bconst, slope2, oA0, oA1, lsA);
            tile_step<false>(kcur, vf, qfB, j0, il, hi, i0B + il, bconst, slope2, oB0, oB1, lsB);
        } else if (kt == tiA) {
            tile_step<true >(kcur, vf, qfA, j0, il, hi, i0A + il, bconst, slope2, oA0, oA1, lsA);
            tile_step<false>(kcur, vf, qfB, j0, il, hi, i0B + il, bconst, slope2, oB0, oB1, lsB);
        } else {    // kt == tiB
            tile_step<true >(kcur, vf, qfB, j0, il, hi, i0B + il, bconst, slope2, oB0, oB1, lsB);
        }
        kcur = knxt;
    }
    write_tile(po, pl, sp, bh, i0A, il, hi, oA0, oA1, lsA);
    write_tile(po, pl, sp, bh, i0B, il, hi, oB0, oB1, lsB);
}

// ---------------------------------------------------------------------------
// Merge 4 splits (vectorized, 4 d's per thread); write bf16 [b, n, h*64+d].
// ---------------------------------------------------------------------------
__global__ __launch_bounds__(256) void merge_kernel(
    const float* __restrict__ pl, const float* __restrict__ po,
    bf16* __restrict__ attnb)
{
    int idx = blockIdx.x * 256 + threadIdx.x;   // 0 .. 16*2048*16-1
    int d = (idx & 15) * 4;
    int rbh = idx >> 4;                         // bh*2048 + n
    int n  = rbh & (NSEQ - 1);
    int bh = rbh >> 11;
    const size_t S = (size_t)(BATCH * HEADS) * NSEQ;  // 32768
    float l = 0.0f;
    float ox = 0, oy = 0, oz = 0, ow = 0;
    #pragma unroll
    for (int s = 0; s < 4; s++) {
        l += pl[(size_t)s * S + rbh];
        float4 p = *(const float4*)(po + ((size_t)s * S + rbh) * DH + d);
        ox += p.x; oy += p.y; oz += p.z; ow += p.w;
    }
    float inv = 1.0f / l;
    int b = bh >> 3, h = bh & 7;
    short4v o;
    o[0] = f2b(ox * inv); o[1] = f2b(oy * inv);
    o[2] = f2b(oz * inv); o[3] = f2b(ow * inv);
    *(short4v*)(attnb + ((size_t)(b * NSEQ + n)) * DIM + h * DH + d) = o;
}

// ---------------------------------------------------------------------------
extern "C" void kernel_launch(void* const* d_in, const int* in_sizes, int n_in,
                              void* d_out, int out_size, void* d_ws, size_t ws_size,
                              hipStream_t stream)
{
    (void)in_sizes; (void)n_in; (void)out_size; (void)ws_size;
    const float* x     = (const float*)d_in[0];
    const float* gamma = (const float*)d_in[1];
    const float* beta  = (const float*)d_in[2];
    const float* wq1   = (const float*)d_in[3];
    const float* wqd   = (const float*)d_in[4];
    const float* wk1   = (const float*)d_in[5];
    const float* wkd   = (const float*)d_in[6];
    const float* wv1   = (const float*)d_in[7];
    const float* wvd   = (const float*)d_in[8];
    const float* wout  = (const float*)d_in[9];
    float* out = (float*)d_out;
    char* base = (char*)d_ws;

    const size_t MB = 1 << 20;
    bf16*  xnb   = (bf16*)(base);                 // 4 MB
    bf16*  Wcat  = (bf16*)(base + 4 * MB);        // 1.5 MB
    bf16*  woutb = (bf16*)(base + 6 * MB);        // 0.5 MB
    bf16*  qb    = (bf16*)(base + 7 * MB);        // 4 MB
    bf16*  kb    = (bf16*)(base + 11 * MB);       // 4 MB
    bf16*  vb    = (bf16*)(base + 15 * MB);       // 4 MB
    bf16*  vtb   = (bf16*)(base + 19 * MB);       // 4 MB
    bf16*  attnb = (bf16*)(base + 23 * MB);       // 4 MB
    float* pl    = (float*)(base + 27 * MB);      // 0.5 MB
    float* ycat  = (float*)(base + 32 * MB);      // 24 MB (dead after dwconv)
    float* po    = (float*)(base + 32 * MB);      // 32 MB (overlaps ycat)

    ln_convert<<<NTOK + 2048, 128, 0, stream>>>(
        x, gamma, beta, xnb, wq1, wk1, wv1, wout, Wcat, woutb);
    gemm_bf16_nt<128><<<dim3(NPROJ / 128, NTOK / 128), 256, 0, stream>>>(
        xnb, Wcat, ycat, NPROJ, DIM);
    dwconv_kernel<<<dim3(NTOK * 128 / 256, 1, 3), 256, 0, stream>>>(
        ycat, wqd, wkd, wvd, qb, kb, vb);
    vtrans_kernel<<<dim3(NSEQ / 64, BATCH * HEADS), 256, 0, stream>>>(vb, vtb);
    attn_mfma<<<dim3(32, BATCH * HEADS, 4), 64, 0, stream>>>(qb, kb, vtb, po, pl);
    merge_kernel<<<(BATCH * HEADS * NSEQ * 16) / 256, 256, 0, stream>>>(pl, po, attnb);
    gemm_bf16_nt<64><<<dim3(DIM / 64, NTOK / 128), 256, 0, stream>>>(
        attnb, woutb, out, DIM, DIM);
}